// Round 10
// baseline (620.161 us; speedup 1.0000x reference)
//
#include <hip/hip_runtime.h>
#include <hip/hip_bf16.h>

#define NB 32
#define SS 1024
#define DD 768

typedef __attribute__((ext_vector_type(8))) short bf16x8;
typedef __attribute__((ext_vector_type(4))) float f32x4;

__device__ inline ushort f2bf(float f) {
    union { float f; unsigned u; } x;
    x.f = f;
    unsigned r = (x.u + 0x7fffu + ((x.u >> 16) & 1u)) >> 16;
    return (ushort)r;
}

#define GLOBAL_PTR(x) ((const __attribute__((address_space(1))) void*)(x))
#define LDS_PTR(x)    ((__attribute__((address_space(3))) void*)(x))

// ---------------------------------------------------------------- K0: f32 -> bf16 flat convert of wq and wk
__global__ void k_cvt(const float* __restrict__ wq, const float* __restrict__ wk,
                      ushort* __restrict__ wqb, ushort* __restrict__ wkb) {
    const int i = (blockIdx.x * 256 + threadIdx.x) * 4;
    const float* src = blockIdx.y ? wk : wq;
    ushort* dst = blockIdx.y ? wkb : wqb;
    const float4 v = *(const float4*)(src + i);
    ushort4 o;
    o.x = f2bf(v.x); o.y = f2bf(v.y); o.z = f2bf(v.z); o.w = f2bf(v.w);
    *(ushort4*)(dst + i) = o;
}

// ---------------------------------------------------------------- K0b: x = bf16(emb[tokens])  (32768 x 768)
__global__ void k_gather(const int* __restrict__ tokens, const float* __restrict__ emb,
                         ushort* __restrict__ xb) {
    int i = (blockIdx.x * 256 + threadIdx.x) * 4;
    int row = i / DD;
    int col = i - row * DD;
    int tok = tokens[row];
    const float4 v = *(const float4*)(emb + (size_t)tok * DD + col);
    ushort4 o;
    o.x = f2bf(v.x); o.y = f2bf(v.y); o.z = f2bf(v.z); o.w = f2bf(v.w);
    *(ushort4*)(xb + (size_t)row * DD + col) = o;
}

// ---------------------------------------------------------------- 128x128 GEMM (m97 structure, dbuf): C = A@Bt^T, bf16 out
__global__ __launch_bounds__(256, 2) void k_gemm_s(const ushort* __restrict__ A,
                                                   const ushort* __restrict__ Bt,
                                                   ushort* __restrict__ Cb) {
    constexpr int BK = 64;
    __shared__ ushort As[2][128 * BK];
    __shared__ ushort Bs[2][128 * BK];
    const int tid = threadIdx.x;
    const int wave = tid >> 6, lane = tid & 63;
    const int bx = blockIdx.x, by = blockIdx.y;
    const size_t abase = (size_t)bx * 128 * DD;
    const size_t bbase = (size_t)by * 128 * DD;
    const int r = tid >> 3;
    const int cc = (tid & 7) * 8;

    auto stage = [&](int buf, int k0) {
#pragma unroll
        for (int i = 0; i < 4; i++) {
            __builtin_amdgcn_global_load_lds(GLOBAL_PTR(A + abase + (size_t)(r + i * 32) * DD + k0 + cc),
                                             LDS_PTR(&As[buf][(r + i * 32) * BK + cc]), 16, 0, 0);
            __builtin_amdgcn_global_load_lds(GLOBAL_PTR(Bt + bbase + (size_t)(r + i * 32) * DD + k0 + cc),
                                             LDS_PTR(&Bs[buf][(r + i * 32) * BK + cc]), 16, 0, 0);
        }
    };

    f32x4 acc[4][4] = {};
    const int wm = (wave >> 1) * 64, wn = (wave & 1) * 64;
    const int lr = lane & 15, lc = (lane >> 4) * 8;

    stage(0, 0);
    __syncthreads();
    int cur = 0;
#pragma unroll 1
    for (int k0 = 0; k0 < DD; k0 += BK) {
        if (k0 + BK < DD) stage(cur ^ 1, k0 + BK);
        const ushort* as = As[cur];
        const ushort* bs = Bs[cur];
#pragma unroll
        for (int kk = 0; kk < 2; kk++) {
            bf16x8 af[4], bfv[4];
#pragma unroll
            for (int m = 0; m < 4; m++)
                af[m] = *(const bf16x8*)(as + (wm + m * 16 + lr) * BK + kk * 32 + lc);
#pragma unroll
            for (int n = 0; n < 4; n++)
                bfv[n] = *(const bf16x8*)(bs + (wn + n * 16 + lr) * BK + kk * 32 + lc);
#pragma unroll
            for (int m = 0; m < 4; m++)
#pragma unroll
                for (int n = 0; n < 4; n++)
                    acc[m][n] = __builtin_amdgcn_mfma_f32_16x16x32_bf16(af[m], bfv[n], acc[m][n], 0, 0, 0);
        }
        __syncthreads();
        cur ^= 1;
    }
    const int rowbase = bx * 128 + wm + (lane >> 4) * 4;
    const int colbase = by * 128 + wn + (lane & 15);
#pragma unroll
    for (int m = 0; m < 4; m++)
#pragma unroll
        for (int n = 0; n < 4; n++)
#pragma unroll
            for (int j = 0; j < 4; j++)
                Cb[(size_t)(rowbase + m * 16 + j) * DD + colbase + n * 16] = f2bf(acc[m][n][j]);
}

// ---------------------------------------------------------------- fused QK^T + masked softmax, 128x1024 tile, 16 waves
// block = 128 rows x full 1024 cols; 16 waves as 2 row-groups x 8 col-groups
// (per wave 64x128, acc[4][8]); A staged once in LDS (no duplication), BK=32
// dbuf, 2-phase (stage t+1 -> compute t -> one barrier). grid 256 = 1 round.
// Mapping: XCD x = wgid&7 hosts batches {x, x+8, x+16, x+24} (all 8 rowblocks
// of a batch on one XCD -> x-panel shared in its L2).
__global__ __launch_bounds__(1024) void k_attn(const ushort* __restrict__ Y,
                                               const ushort* __restrict__ X,
                                               const int* __restrict__ mask,
                                               float* __restrict__ Aout) {
    __shared__ ushort Bsh[2][SS * 32];    // 2 x 64 KB (swizzled 64B rows)
    __shared__ ushort Ash[2][128 * 32];   // 2 x 8 KB
    __shared__ int    Msk[SS];            // 4 KB
    __shared__ float  RedM[8][128];       // 4 KB
    __shared__ float  RedS[8][128];       // 4 KB   -> total 156 KB

    const int tid = threadIdx.x;
    const int wid = tid >> 6, lane = tid & 63;
    const int la = lane & 15, lg = lane >> 4;
    const int wm = wid & 1, wn = wid >> 1;          // row-group 0..1, col-group 0..7

    const int wgid = blockIdx.x;
    const int x = wgid & 7, k = wgid >> 3;
    const int b = x + 8 * (k >> 3);                 // batch
    const int bx = k & 7;                           // row-block 0..7
    const ushort* Ag = Y + (size_t)b * SS * DD + (size_t)bx * 128 * DD;
    const ushort* Bg = X + (size_t)b * SS * DD;
    float* Ao = Aout + (size_t)b * SS * SS + (size_t)bx * 128 * SS;

    Msk[tid] = mask[b * SS + tid];

    // staging: linear LDS dest + pre-swizzled global source (rule #21).
    // 64B rows; chunk c stored at c ^ (r&3).
    auto stageB = [&](ushort* dst, int k0) {
#pragma unroll
        for (int i = 0; i < 4; i++) {
            const int idx = i * 1024 + tid;          // 16B chunk index 0..4095
            const int r = idx >> 2;                  // row 0..1023
            const int scol = ((idx & 3) ^ (r & 3)) << 3;
            __builtin_amdgcn_global_load_lds(GLOBAL_PTR(Bg + (size_t)r * DD + k0 + scol),
                                             LDS_PTR(dst + idx * 8), 16, 0, 0);
        }
    };
    auto stageA = [&](ushort* dst, int k0) {
        if (tid < 512) {
            const int r = tid >> 2;                  // row 0..127
            const int scol = ((tid & 3) ^ (r & 3)) << 3;
            __builtin_amdgcn_global_load_lds(GLOBAL_PTR(Ag + (size_t)r * DD + k0 + scol),
                                             LDS_PTR(dst + tid * 8), 16, 0, 0);
        }
    };

    // read-side: chunk lg of row rr lives at chunk lg ^ (rr&3); rr&3 == la&3
    const int koff = (lg ^ (la & 3)) << 3;

    f32x4 acc[4][8] = {};

    stageB(&Bsh[0][0], 0);
    stageA(&Ash[0][0], 0);
    __syncthreads();   // slice 0 ready (vmcnt(0) drain) + Msk visible

#pragma unroll 1
    for (int t = 0; t < 24; t++) {
        if (t < 23) {
            stageB(&Bsh[(t + 1) & 1][0], (t + 1) * 32);
            stageA(&Ash[(t + 1) & 1][0], (t + 1) * 32);
        }
        const ushort* ash = &Ash[t & 1][0];
        const ushort* bsh = &Bsh[t & 1][0];
        bf16x8 af[4];
#pragma unroll
        for (int m = 0; m < 4; m++)
            af[m] = *(const bf16x8*)(ash + (wm * 64 + m * 16 + la) * 32 + koff);
#pragma unroll
        for (int n = 0; n < 8; n++) {
            const bf16x8 bf = *(const bf16x8*)(bsh + (wn * 128 + n * 16 + la) * 32 + koff);
            __builtin_amdgcn_s_setprio(1);
#pragma unroll
            for (int m = 0; m < 4; m++)
                acc[m][n] = __builtin_amdgcn_mfma_f32_16x16x32_bf16(af[m], bf, acc[m][n], 0, 0, 0);
            __builtin_amdgcn_s_setprio(0);
        }
        __syncthreads();   // drains prefetch; protects dbuf swap
    }

    // ---- in-block masked softmax over full rows ----
    float bias[8];
#pragma unroll
    for (int n = 0; n < 8; n++)
        bias[n] = Msk[wn * 128 + n * 16 + la] ? -1e9f : 0.0f;

    float mxl[4][4];
#pragma unroll
    for (int m = 0; m < 4; m++)
#pragma unroll
        for (int j = 0; j < 4; j++) {
            float v = -3.4e38f;
#pragma unroll
            for (int n = 0; n < 8; n++) v = fmaxf(v, acc[m][n][j] + bias[n]);
#pragma unroll
            for (int off = 1; off < 16; off <<= 1) v = fmaxf(v, __shfl_xor(v, off));
            mxl[m][j] = v;
        }
    if (la == 0) {
#pragma unroll
        for (int m = 0; m < 4; m++)
#pragma unroll
            for (int j = 0; j < 4; j++)
                RedM[wn][wm * 64 + m * 16 + lg * 4 + j] = mxl[m][j];
    }
    __syncthreads();
#pragma unroll
    for (int m = 0; m < 4; m++)
#pragma unroll
        for (int j = 0; j < 4; j++) {
            const int r = wm * 64 + m * 16 + lg * 4 + j;
            float v = RedM[0][r];
#pragma unroll
            for (int ww = 1; ww < 8; ww++) v = fmaxf(v, RedM[ww][r]);
            mxl[m][j] = v;
        }

    float sml[4][4];
#pragma unroll
    for (int m = 0; m < 4; m++)
#pragma unroll
        for (int j = 0; j < 4; j++) {
            float s = 0.f;
#pragma unroll
            for (int n = 0; n < 8; n++) {
                const float e = __expf(acc[m][n][j] + bias[n] - mxl[m][j]);
                acc[m][n][j] = e;
                s += e;
            }
#pragma unroll
            for (int off = 1; off < 16; off <<= 1) s += __shfl_xor(s, off);
            sml[m][j] = s;
        }
    if (la == 0) {
#pragma unroll
        for (int m = 0; m < 4; m++)
#pragma unroll
            for (int j = 0; j < 4; j++)
                RedS[wn][wm * 64 + m * 16 + lg * 4 + j] = sml[m][j];
    }
    __syncthreads();
#pragma unroll
    for (int m = 0; m < 4; m++)
#pragma unroll
        for (int j = 0; j < 4; j++) {
            const int r = wm * 64 + m * 16 + lg * 4 + j;
            float s = RedS[0][r];
#pragma unroll
            for (int ww = 1; ww < 8; ww++) s += RedS[ww][r];
            const float inv = 1.0f / s;
#pragma unroll
            for (int n = 0; n < 8; n++)
                Ao[(size_t)r * SS + wn * 128 + n * 16 + la] = acc[m][n][j] * inv;
        }
}

// ---------------------------------------------------------------- K4a: partial xbar[b][k] = sum_t a[b,0,t]*emb[tok[b,t]][k]
__global__ __launch_bounds__(256) void k_xbar(const float* __restrict__ a, const int* __restrict__ tokens,
                                              const float* __restrict__ emb, float* __restrict__ part) {
    const int b = blockIdx.x >> 3, c = blockIdx.x & 7;
    __shared__ float a0s[128];
    __shared__ int toks[128];
    const int tid = threadIdx.x;
    if (tid < 128) {
        a0s[tid] = a[(size_t)b * SS * SS + c * 128 + tid];
        toks[tid] = tokens[b * SS + c * 128 + tid];
    }
    __syncthreads();
    float acc0 = 0.f, acc1 = 0.f, acc2 = 0.f;
#pragma unroll 4
    for (int t = 0; t < 128; t++) {
        const float at = a0s[t];
        const float* er = emb + (size_t)toks[t] * DD;
        acc0 = fmaf(at, er[tid], acc0);
        acc1 = fmaf(at, er[tid + 256], acc1);
        acc2 = fmaf(at, er[tid + 512], acc2);
    }
    float* p = part + ((size_t)c * NB + b) * DD;
    p[tid] = acc0; p[tid + 256] = acc1; p[tid + 512] = acc2;
}

// ---------------------------------------------------------------- K5: cls[b][c] = sum_k xbar[b][k] * wv[k][c]
__global__ __launch_bounds__(128) void k_cls(const float* __restrict__ part, const float* __restrict__ wv,
                                             float* __restrict__ cls) {
    const int b = blockIdx.y, tid = threadIdx.x;
    const int c = blockIdx.x * 128 + tid;
    __shared__ float xb[DD];
#pragma unroll
    for (int j = 0; j < 6; j++) {
        const int k = tid + j * 128;
        float s = 0.f;
#pragma unroll
        for (int p = 0; p < 8; p++) s += part[((size_t)p * NB + b) * DD + k];
        xb[k] = s;
    }
    __syncthreads();
    float acc = 0.f;
#pragma unroll 8
    for (int k = 0; k < DD; k++) acc = fmaf(xb[k], wv[(size_t)k * DD + c], acc);
    cls[(size_t)b * DD + c] = acc;
}

__device__ inline float block_sum256(float v, float* red, int tid) {
#pragma unroll
    for (int off = 32; off; off >>= 1) v += __shfl_xor(v, off);
    __syncthreads();
    if ((tid & 63) == 0) red[tid >> 6] = v;
    __syncthreads();
    return red[0] + red[1] + red[2] + red[3];
}

// ---------------------------------------------------------------- K6: LayerNorm per batch
__global__ __launch_bounds__(256) void k_ln(const float* __restrict__ cls, const float* __restrict__ ln_g,
                                            const float* __restrict__ ln_b, float* __restrict__ hs) {
    const int b = blockIdx.x, tid = threadIdx.x;
    __shared__ float red[4];
    float v[3];
#pragma unroll
    for (int j = 0; j < 3; j++) v[j] = cls[(size_t)b * DD + tid + j * 256];
    const float mu = block_sum256(v[0] + v[1] + v[2], red, tid) * (1.0f / DD);
    float dv = 0.f;
#pragma unroll
    for (int j = 0; j < 3; j++) { const float d = v[j] - mu; dv += d * d; }
    __syncthreads();
    const float var = block_sum256(dv, red, tid) * (1.0f / DD);
    const float sc = 1.0f / sqrtf(var + 1e-5f);
#pragma unroll
    for (int j = 0; j < 3; j++) {
        const int d = tid + j * 256;
        hs[(size_t)b * DD + d] = (v[j] - mu) * sc * ln_g[d] + ln_b[d];
    }
}

// ---------------------------------------------------------------- K7: g = gelu(hs@w1+b1); partial logits per 128-col chunk
__global__ __launch_bounds__(128) void k_mlp(const float* __restrict__ hs, const float* __restrict__ w1,
                                             const float* __restrict__ b1, const float* __restrict__ wh,
                                             float* __restrict__ part_l) {
    const int b = blockIdx.y, tid = threadIdx.x;
    const int j = blockIdx.x * 128 + tid;
    __shared__ float h[DD];
#pragma unroll
    for (int q = 0; q < 6; q++) h[tid + q * 128] = hs[(size_t)b * DD + tid + q * 128];
    __syncthreads();
    float p = b1[j];
#pragma unroll 8
    for (int d = 0; d < DD; d++) p = fmaf(h[d], w1[(size_t)d * DD + j], p);
    const float g = 0.5f * p * (1.0f + erff(p * 0.70710678118654752f));
    float l0 = g * wh[j * 2 + 0];
    float l1 = g * wh[j * 2 + 1];
#pragma unroll
    for (int off = 32; off; off >>= 1) { l0 += __shfl_xor(l0, off); l1 += __shfl_xor(l1, off); }
    __shared__ float r0[2], r1[2];
    if ((tid & 63) == 0) { r0[tid >> 6] = l0; r1[tid >> 6] = l1; }
    __syncthreads();
    if (tid == 0) {
        part_l[((size_t)b * 6 + blockIdx.x) * 2 + 0] = r0[0] + r0[1];
        part_l[((size_t)b * 6 + blockIdx.x) * 2 + 1] = r1[0] + r1[1];
    }
}

// ---------------------------------------------------------------- K8: final logits reduce
__global__ __launch_bounds__(64) void k_final(const float* __restrict__ part_l, const float* __restrict__ bh,
                                              float* __restrict__ out) {
    const int b = threadIdx.x;
    if (b < NB) {
        float l0 = bh[0], l1 = bh[1];
#pragma unroll
        for (int c = 0; c < 6; c++) {
            l0 += part_l[((size_t)b * 6 + c) * 2 + 0];
            l1 += part_l[((size_t)b * 6 + c) * 2 + 1];
        }
        out[b * 2 + 0] = l0;
        out[b * 2 + 1] = l1;
    }
}

// ----------------------------------------------------------------
extern "C" void kernel_launch(void* const* d_in, const int* in_sizes, int n_in,
                              void* d_out, int out_size, void* d_ws, size_t ws_size,
                              hipStream_t stream) {
    const int*   tokens = (const int*)d_in[0];
    const int*   mask   = (const int*)d_in[1];
    const float* emb    = (const float*)d_in[2];
    const float* wq     = (const float*)d_in[3];
    const float* wk     = (const float*)d_in[4];
    const float* wv     = (const float*)d_in[5];
    const float* ln_g   = (const float*)d_in[6];
    const float* ln_b   = (const float*)d_in[7];
    const float* w1     = (const float*)d_in[8];
    const float* b1     = (const float*)d_in[9];
    const float* wh     = (const float*)d_in[10];
    const float* bh     = (const float*)d_in[11];
    float* out = (float*)d_out;

    char* ws = (char*)d_ws;
    const size_t XB = (size_t)NB * SS * DD * 2;   // 50,331,648 B
    const size_t WB = (size_t)DD * DD * 2;        // 1,179,648 B
    ushort* xb  = (ushort*)ws;                    // x bf16
    ushort* yb  = (ushort*)(ws + XB);             // y = x @ W bf16
    ushort* wqb = (ushort*)(ws + 2 * XB);         // wq bf16
    ushort* wkb = (ushort*)(ws + 2 * XB + WB);    // wk bf16
    ushort* Wt  = (ushort*)(ws + 2 * XB + 2 * WB);// Wt[e][d] = (wq wk^T)[d][e] bf16
    char*   p4  = ws + 2 * XB + 3 * WB;
    float*  part   = (float*)p4;                          // 8*32*768*4
    float*  cls    = (float*)(p4 + 786432);               // 32*768*4
    float*  hsb    = (float*)(p4 + 786432 + 98304);       // 32*768*4
    float*  part_l = (float*)(p4 + 786432 + 2 * 98304);   // 32*6*2*4

    float* a_region = out + 64;  // a: B*S*S floats

    k_cvt<<<dim3(576, 2), 256, 0, stream>>>(wq, wk, wqb, wkb);
    k_gather<<<24576, 256, 0, stream>>>(tokens, emb, xb);
    // Wt = wk @ wq^T  (Wt[e][d] = sum_j wk[e,j] wq[d,j] = W[d,e])
    k_gemm_s<<<dim3(6, 6), 256, 0, stream>>>(wkb, wqb, Wt);
    // y = x @ W  (y[s,e] = sum_d x[s,d] Wt[e,d])
    k_gemm_s<<<dim3(256, 6), 256, 0, stream>>>(xb, Wt, yb);
    // a = softmax(y @ x^T + mask), fused, 128x1024 tile / 16 waves
    k_attn<<<256, 1024, 0, stream>>>(yb, xb, mask, a_region);
    k_xbar<<<256, 256, 0, stream>>>(a_region, tokens, emb, part);
    k_cls<<<dim3(6, NB), 128, 0, stream>>>(part, wv, cls);
    k_ln<<<NB, 256, 0, stream>>>(cls, ln_g, ln_b, hsb);
    k_mlp<<<dim3(6, NB), 128, 0, stream>>>(hsb, w1, b1, wh, part_l);
    k_final<<<1, 64, 0, stream>>>(part_l, bh, out);
}

// Round 11
// 334.491 us; speedup vs baseline: 1.8540x; 1.8540x over previous
//
#include <hip/hip_runtime.h>
#include <hip/hip_bf16.h>

#define NB 32
#define SS 1024
#define DD 768

typedef __attribute__((ext_vector_type(8))) short bf16x8;
typedef __attribute__((ext_vector_type(4))) float f32x4;

__device__ inline ushort f2bf(float f) {
    union { float f; unsigned u; } x;
    x.f = f;
    unsigned r = (x.u + 0x7fffu + ((x.u >> 16) & 1u)) >> 16;
    return (ushort)r;
}

__device__ inline float bf2f(ushort u) {
    union { unsigned u; float f; } x;
    x.u = ((unsigned)u) << 16;
    return x.f;
}

#define GLOBAL_PTR(x) ((const __attribute__((address_space(1))) void*)(x))
#define LDS_PTR(x)    ((__attribute__((address_space(3))) void*)(x))

// ---------------------------------------------------------------- K0: f32 -> bf16 flat convert of wq and wk
__global__ void k_cvt(const float* __restrict__ wq, const float* __restrict__ wk,
                      ushort* __restrict__ wqb, ushort* __restrict__ wkb) {
    const int i = (blockIdx.x * 256 + threadIdx.x) * 4;
    const float* src = blockIdx.y ? wk : wq;
    ushort* dst = blockIdx.y ? wkb : wqb;
    const float4 v = *(const float4*)(src + i);
    ushort4 o;
    o.x = f2bf(v.x); o.y = f2bf(v.y); o.z = f2bf(v.z); o.w = f2bf(v.w);
    *(ushort4*)(dst + i) = o;
}

// ---------------------------------------------------------------- K0b: x = bf16(emb[tokens])  (32768 x 768)
__global__ void k_gather(const int* __restrict__ tokens, const float* __restrict__ emb,
                         ushort* __restrict__ xb) {
    int i = (blockIdx.x * 256 + threadIdx.x) * 4;
    int row = i / DD;
    int col = i - row * DD;
    int tok = tokens[row];
    const float4 v = *(const float4*)(emb + (size_t)tok * DD + col);
    ushort4 o;
    o.x = f2bf(v.x); o.y = f2bf(v.y); o.z = f2bf(v.z); o.w = f2bf(v.w);
    *(ushort4*)(xb + (size_t)row * DD + col) = o;
}

// ---------------------------------------------------------------- 128x128 GEMM (m97 structure, dbuf): C = A@Bt^T, bf16 out
__global__ __launch_bounds__(256, 2) void k_gemm_s(const ushort* __restrict__ A,
                                                   const ushort* __restrict__ Bt,
                                                   ushort* __restrict__ Cb) {
    constexpr int BK = 64;
    __shared__ ushort As[2][128 * BK];
    __shared__ ushort Bs[2][128 * BK];
    const int tid = threadIdx.x;
    const int wave = tid >> 6, lane = tid & 63;
    const int bx = blockIdx.x, by = blockIdx.y;
    const size_t abase = (size_t)bx * 128 * DD;
    const size_t bbase = (size_t)by * 128 * DD;
    const int r = tid >> 3;
    const int cc = (tid & 7) * 8;

    auto stage = [&](int buf, int k0) {
#pragma unroll
        for (int i = 0; i < 4; i++) {
            __builtin_amdgcn_global_load_lds(GLOBAL_PTR(A + abase + (size_t)(r + i * 32) * DD + k0 + cc),
                                             LDS_PTR(&As[buf][(r + i * 32) * BK + cc]), 16, 0, 0);
            __builtin_amdgcn_global_load_lds(GLOBAL_PTR(Bt + bbase + (size_t)(r + i * 32) * DD + k0 + cc),
                                             LDS_PTR(&Bs[buf][(r + i * 32) * BK + cc]), 16, 0, 0);
        }
    };

    f32x4 acc[4][4] = {};
    const int wm = (wave >> 1) * 64, wn = (wave & 1) * 64;
    const int lr = lane & 15, lc = (lane >> 4) * 8;

    stage(0, 0);
    __syncthreads();
    int cur = 0;
#pragma unroll 1
    for (int k0 = 0; k0 < DD; k0 += BK) {
        if (k0 + BK < DD) stage(cur ^ 1, k0 + BK);
        const ushort* as = As[cur];
        const ushort* bs = Bs[cur];
#pragma unroll
        for (int kk = 0; kk < 2; kk++) {
            bf16x8 af[4], bfv[4];
#pragma unroll
            for (int m = 0; m < 4; m++)
                af[m] = *(const bf16x8*)(as + (wm + m * 16 + lr) * BK + kk * 32 + lc);
#pragma unroll
            for (int n = 0; n < 4; n++)
                bfv[n] = *(const bf16x8*)(bs + (wn + n * 16 + lr) * BK + kk * 32 + lc);
#pragma unroll
            for (int m = 0; m < 4; m++)
#pragma unroll
                for (int n = 0; n < 4; n++)
                    acc[m][n] = __builtin_amdgcn_mfma_f32_16x16x32_bf16(af[m], bfv[n], acc[m][n], 0, 0, 0);
        }
        __syncthreads();
        cur ^= 1;
    }
    const int rowbase = bx * 128 + wm + (lane >> 4) * 4;
    const int colbase = by * 128 + wn + (lane & 15);
#pragma unroll
    for (int m = 0; m < 4; m++)
#pragma unroll
        for (int n = 0; n < 4; n++)
#pragma unroll
            for (int j = 0; j < 4; j++)
                Cb[(size_t)(rowbase + m * 16 + j) * DD + colbase + n * 16] = f2bf(acc[m][n][j]);
}

// ---------------------------------------------------------------- 256x256 8-wave 4-phase GEMM for batched QK^T (R5-proven)
// s = Y @ X^T per batch. 1-D grid 512, XCD-clustered: epochs of 128 wgs;
// batch = epoch*8 + w%8, tile = (w%128)/8 -> 16 tiles/batch on one XCD.
// OUT=1: bf16 s to Cb (ldc=SS). OUT=0: f32 s to Cs (ldc=SS).
#define HALF_USH (128 * 64)
template <int OUT>
__global__ __launch_bounds__(512, 2) void k_gemm256b(const ushort* __restrict__ A,
                                                     const ushort* __restrict__ Bt,
                                                     ushort* __restrict__ Cb,
                                                     float* __restrict__ Cs) {
    __shared__ ushort As[2][2][HALF_USH];
    __shared__ ushort Bs[2][2][HALF_USH];
    const int tid = threadIdx.x;
    const int wid = tid >> 6, lane = tid & 63;
    const int wm = wid >> 2, wn = wid & 3;
    const int la = lane & 15;

    const int wgid = blockIdx.x;
    const int g = wgid >> 7, w = wgid & 127;
    const int b = g * 8 + (w & 7);
    const int tile = w >> 3;
    const int bx = tile & 3, by = tile >> 2;
    const ushort* Ag = A + (size_t)b * SS * DD + (size_t)bx * 256 * DD;
    const ushort* Bg = Bt + (size_t)b * SS * DD + (size_t)by * 256 * DD;
    if (OUT) Cb += (size_t)b * SS * SS;
    else     Cs += (size_t)b * SS * SS;

    int s_r[2], s_c[2], s_d[2];
#pragma unroll
    for (int l = 0; l < 2; l++) {
        const int L = (l * 512 + tid) * 16;
        const int r = L >> 7;
        const int cb = L & 127;
        s_r[l] = r;
        s_c[l] = (cb ^ ((r & 7) << 4)) >> 1;
        s_d[l] = L >> 1;
    }

    auto stage_half = [&](ushort* dst, const ushort* gsrc) {
#pragma unroll
        for (int l = 0; l < 2; l++)
            __builtin_amdgcn_global_load_lds(GLOBAL_PTR(gsrc + (size_t)s_r[l] * DD + s_c[l]),
                                             LDS_PTR(dst + s_d[l]), 16, 0, 0);
    };

    const int swz = (la & 7) << 4;
    const int off_k0 = (((lane >> 4) << 4) ^ swz) >> 1;
    const int off_k1 = ((64 | ((lane >> 4) << 4)) ^ swz) >> 1;

    f32x4 acc[8][4] = {};

    stage_half(&As[0][0][0], Ag);
    stage_half(&As[0][1][0], Ag + (size_t)128 * DD);
    stage_half(&Bs[0][0][0], Bg);
    stage_half(&Bs[0][1][0], Bg + (size_t)128 * DD);
    __syncthreads();

#pragma unroll 1
    for (int t = 0; t < 12; t++) {
        const int buf = t & 1;
        const ushort* Ah = &As[buf][wm][0];
        const ushort* Bh = &Bs[buf][wn >> 1][0];
        const int brow0 = (wn & 1) * 64;
        const int kt = (t + 1) * 64;
        bf16x8 bfv[4][2];
#pragma unroll
        for (int q = 0; q < 4; q++) {
            if (q == 0) {
#pragma unroll
                for (int n = 0; n < 4; n++) {
                    const int rr = brow0 + n * 16 + la;
                    bfv[n][0] = *(const bf16x8*)(Bh + rr * 64 + off_k0);
                    bfv[n][1] = *(const bf16x8*)(Bh + rr * 64 + off_k1);
                }
            }
            bf16x8 af[2][2];
#pragma unroll
            for (int dm = 0; dm < 2; dm++) {
                const int rr = (q * 2 + dm) * 16 + la;
                af[dm][0] = *(const bf16x8*)(Ah + rr * 64 + off_k0);
                af[dm][1] = *(const bf16x8*)(Ah + rr * 64 + off_k1);
            }
            if (t < 11) {
                if (q == 0) stage_half(&As[buf ^ 1][0][0], Ag + kt);
                if (q == 1) stage_half(&As[buf ^ 1][1][0], Ag + (size_t)128 * DD + kt);
                if (q == 2) stage_half(&Bs[buf ^ 1][0][0], Bg + kt);
                if (q == 3) stage_half(&Bs[buf ^ 1][1][0], Bg + (size_t)128 * DD + kt);
            }
            __builtin_amdgcn_s_setprio(1);
#pragma unroll
            for (int dm = 0; dm < 2; dm++)
#pragma unroll
                for (int n = 0; n < 4; n++)
#pragma unroll
                    for (int kk = 0; kk < 2; kk++)
                        acc[q * 2 + dm][n] = __builtin_amdgcn_mfma_f32_16x16x32_bf16(
                            af[dm][kk], bfv[n][kk], acc[q * 2 + dm][n], 0, 0, 0);
            __builtin_amdgcn_s_setprio(0);
            if (q < 3) __builtin_amdgcn_s_barrier();
        }
        __syncthreads();
    }

    const int rowbase = bx * 256 + wm * 128 + (lane >> 4) * 4;
    const int colbase = by * 256 + wn * 64 + la;
#pragma unroll
    for (int m = 0; m < 8; m++)
#pragma unroll
        for (int n = 0; n < 4; n++)
#pragma unroll
            for (int j = 0; j < 4; j++) {
                if (OUT) Cb[(size_t)(rowbase + m * 16 + j) * SS + colbase + n * 16] = f2bf(acc[m][n][j]);
                else     Cs[(size_t)(rowbase + m * 16 + j) * SS + colbase + n * 16] = acc[m][n][j];
            }
}

// ---------------------------------------------------------------- masked softmax, one wave per row, no max pass (|s| small),
// no LDS, no barriers. BF=1: read bf16 s from sv; BF=0: f32 in-place from a.
template <int BF>
__global__ __launch_bounds__(256) void k_smax(const void* __restrict__ sv, const int* __restrict__ mask,
                                              float* __restrict__ a) {
    const int tid = threadIdx.x, lane = tid & 63;
    const int row = blockIdx.x * 4 + (tid >> 6);
    const int b = row >> 10;
    const size_t base = (size_t)row * SS;
    const int* mrow = mask + b * SS;

    float e[4][4];
    float psum = 0.f;
#pragma unroll
    for (int g = 0; g < 4; g++) {
        const int t = g * 256 + lane * 4;
        const int4 mk = *(const int4*)(mrow + t);
        float v0, v1, v2, v3;
        if (BF) {
            const ushort4 sv4 = *(const ushort4*)((const ushort*)sv + base + t);
            v0 = bf2f(sv4.x); v1 = bf2f(sv4.y); v2 = bf2f(sv4.z); v3 = bf2f(sv4.w);
        } else {
            const float4 sf = *(const float4*)((const float*)sv + base + t);
            v0 = sf.x; v1 = sf.y; v2 = sf.z; v3 = sf.w;
        }
        e[g][0] = __expf(v0 + (mk.x ? -1e9f : 0.0f));
        e[g][1] = __expf(v1 + (mk.y ? -1e9f : 0.0f));
        e[g][2] = __expf(v2 + (mk.z ? -1e9f : 0.0f));
        e[g][3] = __expf(v3 + (mk.w ? -1e9f : 0.0f));
        psum += e[g][0] + e[g][1] + e[g][2] + e[g][3];
    }
#pragma unroll
    for (int off = 32; off; off >>= 1) psum += __shfl_xor(psum, off);
    const float inv = 1.0f / psum;
#pragma unroll
    for (int g = 0; g < 4; g++) {
        const int t = g * 256 + lane * 4;
        float4 o;
        o.x = e[g][0] * inv; o.y = e[g][1] * inv; o.z = e[g][2] * inv; o.w = e[g][3] * inv;
        *(float4*)(a + base + t) = o;
    }
}

// ---------------------------------------------------------------- K4a: partial xbar[b][k] = sum_t a[b,0,t]*emb[tok[b,t]][k]
__global__ __launch_bounds__(256) void k_xbar(const float* __restrict__ a, const int* __restrict__ tokens,
                                              const float* __restrict__ emb, float* __restrict__ part) {
    const int b = blockIdx.x >> 3, c = blockIdx.x & 7;
    __shared__ float a0s[128];
    __shared__ int toks[128];
    const int tid = threadIdx.x;
    if (tid < 128) {
        a0s[tid] = a[(size_t)b * SS * SS + c * 128 + tid];
        toks[tid] = tokens[b * SS + c * 128 + tid];
    }
    __syncthreads();
    float acc0 = 0.f, acc1 = 0.f, acc2 = 0.f;
#pragma unroll 4
    for (int t = 0; t < 128; t++) {
        const float at = a0s[t];
        const float* er = emb + (size_t)toks[t] * DD;
        acc0 = fmaf(at, er[tid], acc0);
        acc1 = fmaf(at, er[tid + 256], acc1);
        acc2 = fmaf(at, er[tid + 512], acc2);
    }
    float* p = part + ((size_t)c * NB + b) * DD;
    p[tid] = acc0; p[tid + 256] = acc1; p[tid + 512] = acc2;
}

// ---------------------------------------------------------------- K5: cls[b][c] = sum_k xbar[b][k] * wv[k][c]
__global__ __launch_bounds__(128) void k_cls(const float* __restrict__ part, const float* __restrict__ wv,
                                             float* __restrict__ cls) {
    const int b = blockIdx.y, tid = threadIdx.x;
    const int c = blockIdx.x * 128 + tid;
    __shared__ float xb[DD];
#pragma unroll
    for (int j = 0; j < 6; j++) {
        const int k = tid + j * 128;
        float s = 0.f;
#pragma unroll
        for (int p = 0; p < 8; p++) s += part[((size_t)p * NB + b) * DD + k];
        xb[k] = s;
    }
    __syncthreads();
    float acc = 0.f;
#pragma unroll 8
    for (int k = 0; k < DD; k++) acc = fmaf(xb[k], wv[(size_t)k * DD + c], acc);
    cls[(size_t)b * DD + c] = acc;
}

__device__ inline float block_sum256(float v, float* red, int tid) {
#pragma unroll
    for (int off = 32; off; off >>= 1) v += __shfl_xor(v, off);
    __syncthreads();
    if ((tid & 63) == 0) red[tid >> 6] = v;
    __syncthreads();
    return red[0] + red[1] + red[2] + red[3];
}

// ---------------------------------------------------------------- K6: LayerNorm per batch
__global__ __launch_bounds__(256) void k_ln(const float* __restrict__ cls, const float* __restrict__ ln_g,
                                            const float* __restrict__ ln_b, float* __restrict__ hs) {
    const int b = blockIdx.x, tid = threadIdx.x;
    __shared__ float red[4];
    float v[3];
#pragma unroll
    for (int j = 0; j < 3; j++) v[j] = cls[(size_t)b * DD + tid + j * 256];
    const float mu = block_sum256(v[0] + v[1] + v[2], red, tid) * (1.0f / DD);
    float dv = 0.f;
#pragma unroll
    for (int j = 0; j < 3; j++) { const float d = v[j] - mu; dv += d * d; }
    __syncthreads();
    const float var = block_sum256(dv, red, tid) * (1.0f / DD);
    const float sc = 1.0f / sqrtf(var + 1e-5f);
#pragma unroll
    for (int j = 0; j < 3; j++) {
        const int d = tid + j * 256;
        hs[(size_t)b * DD + d] = (v[j] - mu) * sc * ln_g[d] + ln_b[d];
    }
}

// ---------------------------------------------------------------- K7: g = gelu(hs@w1+b1); partial logits per 128-col chunk
__global__ __launch_bounds__(128) void k_mlp(const float* __restrict__ hs, const float* __restrict__ w1,
                                             const float* __restrict__ b1, const float* __restrict__ wh,
                                             float* __restrict__ part_l) {
    const int b = blockIdx.y, tid = threadIdx.x;
    const int j = blockIdx.x * 128 + tid;
    __shared__ float h[DD];
#pragma unroll
    for (int q = 0; q < 6; q++) h[tid + q * 128] = hs[(size_t)b * DD + tid + q * 128];
    __syncthreads();
    float p = b1[j];
#pragma unroll 8
    for (int d = 0; d < DD; d++) p = fmaf(h[d], w1[(size_t)d * DD + j], p);
    const float g = 0.5f * p * (1.0f + erff(p * 0.70710678118654752f));
    float l0 = g * wh[j * 2 + 0];
    float l1 = g * wh[j * 2 + 1];
#pragma unroll
    for (int off = 32; off; off >>= 1) { l0 += __shfl_xor(l0, off); l1 += __shfl_xor(l1, off); }
    __shared__ float r0[2], r1[2];
    if ((tid & 63) == 0) { r0[tid >> 6] = l0; r1[tid >> 6] = l1; }
    __syncthreads();
    if (tid == 0) {
        part_l[((size_t)b * 6 + blockIdx.x) * 2 + 0] = r0[0] + r0[1];
        part_l[((size_t)b * 6 + blockIdx.x) * 2 + 1] = r1[0] + r1[1];
    }
}

// ---------------------------------------------------------------- K8: final logits reduce
__global__ __launch_bounds__(64) void k_final(const float* __restrict__ part_l, const float* __restrict__ bh,
                                              float* __restrict__ out) {
    const int b = threadIdx.x;
    if (b < NB) {
        float l0 = bh[0], l1 = bh[1];
#pragma unroll
        for (int c = 0; c < 6; c++) {
            l0 += part_l[((size_t)b * 6 + c) * 2 + 0];
            l1 += part_l[((size_t)b * 6 + c) * 2 + 1];
        }
        out[b * 2 + 0] = l0;
        out[b * 2 + 1] = l1;
    }
}

// ----------------------------------------------------------------
extern "C" void kernel_launch(void* const* d_in, const int* in_sizes, int n_in,
                              void* d_out, int out_size, void* d_ws, size_t ws_size,
                              hipStream_t stream) {
    const int*   tokens = (const int*)d_in[0];
    const int*   mask   = (const int*)d_in[1];
    const float* emb    = (const float*)d_in[2];
    const float* wq     = (const float*)d_in[3];
    const float* wk     = (const float*)d_in[4];
    const float* wv     = (const float*)d_in[5];
    const float* ln_g   = (const float*)d_in[6];
    const float* ln_b   = (const float*)d_in[7];
    const float* w1     = (const float*)d_in[8];
    const float* b1     = (const float*)d_in[9];
    const float* wh     = (const float*)d_in[10];
    const float* bh     = (const float*)d_in[11];
    float* out = (float*)d_out;

    char* ws = (char*)d_ws;
    const size_t XB = (size_t)NB * SS * DD * 2;   // 50,331,648 B
    const size_t WB = (size_t)DD * DD * 2;        // 1,179,648 B
    const size_t SB = (size_t)NB * SS * SS * 2;   // 67,108,864 B (bf16 s)
    ushort* xb = (ushort*)ws;                     // x bf16
    ushort* yb = (ushort*)(ws + XB);              // y = x @ W bf16

    // small buffers share the sb region (lifetimes disjoint from sb):
    // wqb/wkb/Wt die before gemm1 writes sb; part/cls/hsb live after smax reads sb.
    char*   sreg = ws + 2 * XB;
    ushort* sb   = (ushort*)sreg;                 // bf16 s (67 MB), bf16 path only
    ushort* wqb  = (ushort*)sreg;
    ushort* wkb  = (ushort*)(sreg + WB);
    ushort* Wt   = (ushort*)(sreg + 2 * WB);
    char*   p4   = sreg + 3 * WB;
    float*  part   = (float*)p4;                          // 8*32*768*4
    float*  cls    = (float*)(p4 + 786432);               // 32*768*4
    float*  hsb    = (float*)(p4 + 786432 + 98304);       // 32*768*4
    float*  part_l = (float*)(p4 + 786432 + 2 * 98304);   // 32*6*2*4

    float* a_region = out + 64;  // a: B*S*S floats

    const bool bf16s = ws_size >= 2 * XB + SB;

    k_cvt<<<dim3(576, 2), 256, 0, stream>>>(wq, wk, wqb, wkb);
    k_gather<<<24576, 256, 0, stream>>>(tokens, emb, xb);
    // Wt = wk @ wq^T  (Wt[e][d] = sum_j wk[e,j] wq[d,j] = W[d,e])
    k_gemm_s<<<dim3(6, 6), 256, 0, stream>>>(wkb, wqb, Wt);
    // y = x @ W  (balanced 1536-block grid, 2 blocks/CU)
    k_gemm_s<<<dim3(256, 6), 256, 0, stream>>>(xb, Wt, yb);
    // s = y @ x^T (batched, XCD-clustered); then softmax
    if (bf16s) {
        k_gemm256b<1><<<512, 512, 0, stream>>>(yb, xb, sb, nullptr);
        k_smax<1><<<8192, 256, 0, stream>>>(sb, mask, a_region);
    } else {
        k_gemm256b<0><<<512, 512, 0, stream>>>(yb, xb, nullptr, a_region);
        k_smax<0><<<8192, 256, 0, stream>>>(a_region, mask, a_region);
    }
    k_xbar<<<256, 256, 0, stream>>>(a_region, tokens, emb, part);
    k_cls<<<dim3(6, NB), 128, 0, stream>>>(part, wv, cls);
    k_ln<<<NB, 256, 0, stream>>>(cls, ln_g, ln_b, hsb);
    k_mlp<<<dim3(6, NB), 128, 0, stream>>>(hsb, w1, b1, wh, part_l);
    k_final<<<1, 64, 0, stream>>>(part_l, bh, out);
}

// Round 12
// 328.308 us; speedup vs baseline: 1.8890x; 1.0188x over previous
//
#include <hip/hip_runtime.h>
#include <hip/hip_bf16.h>

#define NB 32
#define SS 1024
#define DD 768

typedef __attribute__((ext_vector_type(8))) short bf16x8;
typedef __attribute__((ext_vector_type(4))) float f32x4;

__device__ inline ushort f2bf(float f) {
    union { float f; unsigned u; } x;
    x.f = f;
    unsigned r = (x.u + 0x7fffu + ((x.u >> 16) & 1u)) >> 16;
    return (ushort)r;
}

__device__ inline float bf2f(ushort u) {
    union { unsigned u; float f; } x;
    x.u = ((unsigned)u) << 16;
    return x.f;
}

#define GLOBAL_PTR(x) ((const __attribute__((address_space(1))) void*)(x))
#define LDS_PTR(x)    ((__attribute__((address_space(3))) void*)(x))

// ---------------------------------------------------------------- K0: f32 -> bf16 flat convert of wq and wk
__global__ void k_cvt(const float* __restrict__ wq, const float* __restrict__ wk,
                      ushort* __restrict__ wqb, ushort* __restrict__ wkb) {
    const int i = (blockIdx.x * 256 + threadIdx.x) * 4;
    const float* src = blockIdx.y ? wk : wq;
    ushort* dst = blockIdx.y ? wkb : wqb;
    const float4 v = *(const float4*)(src + i);
    ushort4 o;
    o.x = f2bf(v.x); o.y = f2bf(v.y); o.z = f2bf(v.z); o.w = f2bf(v.w);
    *(ushort4*)(dst + i) = o;
}

// ---------------------------------------------------------------- K0b: x = bf16(emb[tokens])  (32768 x 768)
__global__ void k_gather(const int* __restrict__ tokens, const float* __restrict__ emb,
                         ushort* __restrict__ xb) {
    int i = (blockIdx.x * 256 + threadIdx.x) * 4;
    int row = i / DD;
    int col = i - row * DD;
    int tok = tokens[row];
    const float4 v = *(const float4*)(emb + (size_t)tok * DD + col);
    ushort4 o;
    o.x = f2bf(v.x); o.y = f2bf(v.y); o.z = f2bf(v.z); o.w = f2bf(v.w);
    *(ushort4*)(xb + (size_t)row * DD + col) = o;
}

// ---------------------------------------------------------------- 128x128 GEMM (m97 structure, dbuf): C = A@Bt^T, bf16 out
__global__ __launch_bounds__(256, 2) void k_gemm_s(const ushort* __restrict__ A,
                                                   const ushort* __restrict__ Bt,
                                                   ushort* __restrict__ Cb) {
    constexpr int BK = 64;
    __shared__ ushort As[2][128 * BK];
    __shared__ ushort Bs[2][128 * BK];
    const int tid = threadIdx.x;
    const int wave = tid >> 6, lane = tid & 63;
    const int bx = blockIdx.x, by = blockIdx.y;
    const size_t abase = (size_t)bx * 128 * DD;
    const size_t bbase = (size_t)by * 128 * DD;
    const int r = tid >> 3;
    const int cc = (tid & 7) * 8;

    auto stage = [&](int buf, int k0) {
#pragma unroll
        for (int i = 0; i < 4; i++) {
            __builtin_amdgcn_global_load_lds(GLOBAL_PTR(A + abase + (size_t)(r + i * 32) * DD + k0 + cc),
                                             LDS_PTR(&As[buf][(r + i * 32) * BK + cc]), 16, 0, 0);
            __builtin_amdgcn_global_load_lds(GLOBAL_PTR(Bt + bbase + (size_t)(r + i * 32) * DD + k0 + cc),
                                             LDS_PTR(&Bs[buf][(r + i * 32) * BK + cc]), 16, 0, 0);
        }
    };

    f32x4 acc[4][4] = {};
    const int wm = (wave >> 1) * 64, wn = (wave & 1) * 64;
    const int lr = lane & 15, lc = (lane >> 4) * 8;

    stage(0, 0);
    __syncthreads();
    int cur = 0;
#pragma unroll 1
    for (int k0 = 0; k0 < DD; k0 += BK) {
        if (k0 + BK < DD) stage(cur ^ 1, k0 + BK);
        const ushort* as = As[cur];
        const ushort* bs = Bs[cur];
#pragma unroll
        for (int kk = 0; kk < 2; kk++) {
            bf16x8 af[4], bfv[4];
#pragma unroll
            for (int m = 0; m < 4; m++)
                af[m] = *(const bf16x8*)(as + (wm + m * 16 + lr) * BK + kk * 32 + lc);
#pragma unroll
            for (int n = 0; n < 4; n++)
                bfv[n] = *(const bf16x8*)(bs + (wn + n * 16 + lr) * BK + kk * 32 + lc);
#pragma unroll
            for (int m = 0; m < 4; m++)
#pragma unroll
                for (int n = 0; n < 4; n++)
                    acc[m][n] = __builtin_amdgcn_mfma_f32_16x16x32_bf16(af[m], bfv[n], acc[m][n], 0, 0, 0);
        }
        __syncthreads();
        cur ^= 1;
    }
    const int rowbase = bx * 128 + wm + (lane >> 4) * 4;
    const int colbase = by * 128 + wn + (lane & 15);
#pragma unroll
    for (int m = 0; m < 4; m++)
#pragma unroll
        for (int n = 0; n < 4; n++)
#pragma unroll
            for (int j = 0; j < 4; j++)
                Cb[(size_t)(rowbase + m * 16 + j) * DD + colbase + n * 16] = f2bf(acc[m][n][j]);
}

// ---------------------------------------------------------------- 256x256 8-wave 4-phase GEMM for batched QK^T (R5-proven
// schedule, unchanged). Output: bf16 s interleaved into the f32 a-region:
// row r's bf16 s occupies the FIRST 2KB of row r's 4KB slot (row stride 2048 ushorts).
#define HALF_USH (128 * 64)
__global__ __launch_bounds__(512, 2) void k_gemm256b(const ushort* __restrict__ A,
                                                     const ushort* __restrict__ Bt,
                                                     ushort* __restrict__ Cu) {
    __shared__ ushort As[2][2][HALF_USH];
    __shared__ ushort Bs[2][2][HALF_USH];
    const int tid = threadIdx.x;
    const int wid = tid >> 6, lane = tid & 63;
    const int wm = wid >> 2, wn = wid & 3;
    const int la = lane & 15;

    const int wgid = blockIdx.x;
    const int g = wgid >> 7, w = wgid & 127;
    const int b = g * 8 + (w & 7);
    const int tile = w >> 3;
    const int bx = tile & 3, by = tile >> 2;
    const ushort* Ag = A + (size_t)b * SS * DD + (size_t)bx * 256 * DD;
    const ushort* Bg = Bt + (size_t)b * SS * DD + (size_t)by * 256 * DD;
    Cu += (size_t)b * SS * 2048;   // batch offset in interleaved layout

    int s_r[2], s_c[2], s_d[2];
#pragma unroll
    for (int l = 0; l < 2; l++) {
        const int L = (l * 512 + tid) * 16;
        const int r = L >> 7;
        const int cb = L & 127;
        s_r[l] = r;
        s_c[l] = (cb ^ ((r & 7) << 4)) >> 1;
        s_d[l] = L >> 1;
    }

    auto stage_half = [&](ushort* dst, const ushort* gsrc) {
#pragma unroll
        for (int l = 0; l < 2; l++)
            __builtin_amdgcn_global_load_lds(GLOBAL_PTR(gsrc + (size_t)s_r[l] * DD + s_c[l]),
                                             LDS_PTR(dst + s_d[l]), 16, 0, 0);
    };

    const int swz = (la & 7) << 4;
    const int off_k0 = (((lane >> 4) << 4) ^ swz) >> 1;
    const int off_k1 = ((64 | ((lane >> 4) << 4)) ^ swz) >> 1;

    f32x4 acc[8][4] = {};

    stage_half(&As[0][0][0], Ag);
    stage_half(&As[0][1][0], Ag + (size_t)128 * DD);
    stage_half(&Bs[0][0][0], Bg);
    stage_half(&Bs[0][1][0], Bg + (size_t)128 * DD);
    __syncthreads();

#pragma unroll 1
    for (int t = 0; t < 12; t++) {
        const int buf = t & 1;
        const ushort* Ah = &As[buf][wm][0];
        const ushort* Bh = &Bs[buf][wn >> 1][0];
        const int brow0 = (wn & 1) * 64;
        const int kt = (t + 1) * 64;
        bf16x8 bfv[4][2];
#pragma unroll
        for (int q = 0; q < 4; q++) {
            if (q == 0) {
#pragma unroll
                for (int n = 0; n < 4; n++) {
                    const int rr = brow0 + n * 16 + la;
                    bfv[n][0] = *(const bf16x8*)(Bh + rr * 64 + off_k0);
                    bfv[n][1] = *(const bf16x8*)(Bh + rr * 64 + off_k1);
                }
            }
            bf16x8 af[2][2];
#pragma unroll
            for (int dm = 0; dm < 2; dm++) {
                const int rr = (q * 2 + dm) * 16 + la;
                af[dm][0] = *(const bf16x8*)(Ah + rr * 64 + off_k0);
                af[dm][1] = *(const bf16x8*)(Ah + rr * 64 + off_k1);
            }
            if (t < 11) {
                if (q == 0) stage_half(&As[buf ^ 1][0][0], Ag + kt);
                if (q == 1) stage_half(&As[buf ^ 1][1][0], Ag + (size_t)128 * DD + kt);
                if (q == 2) stage_half(&Bs[buf ^ 1][0][0], Bg + kt);
                if (q == 3) stage_half(&Bs[buf ^ 1][1][0], Bg + (size_t)128 * DD + kt);
            }
            __builtin_amdgcn_s_setprio(1);
#pragma unroll
            for (int dm = 0; dm < 2; dm++)
#pragma unroll
                for (int n = 0; n < 4; n++)
#pragma unroll
                    for (int kk = 0; kk < 2; kk++)
                        acc[q * 2 + dm][n] = __builtin_amdgcn_mfma_f32_16x16x32_bf16(
                            af[dm][kk], bfv[n][kk], acc[q * 2 + dm][n], 0, 0, 0);
            __builtin_amdgcn_s_setprio(0);
            if (q < 3) __builtin_amdgcn_s_barrier();
        }
        __syncthreads();
    }

    const int rowbase = bx * 256 + wm * 128 + (lane >> 4) * 4;
    const int colbase = by * 256 + wn * 64 + la;
#pragma unroll
    for (int m = 0; m < 8; m++)
#pragma unroll
        for (int n = 0; n < 4; n++)
#pragma unroll
            for (int j = 0; j < 4; j++)
                Cu[(size_t)(rowbase + m * 16 + j) * 2048 + colbase + n * 16] = f2bf(acc[m][n][j]);
}

// ---------------------------------------------------------------- masked softmax: one wave per row; reads bf16 s from the
// first 2KB of the row's own 4KB slot, writes f32 a over the full slot.
// Read-before-write within the same wave -> no races. No max pass (|s| small;
// masked -1e9 underflows to 0 exactly as f32 reference).
__global__ __launch_bounds__(256) void k_smax(const ushort* __restrict__ su, const int* __restrict__ mask,
                                              float* __restrict__ a) {
    const int tid = threadIdx.x, lane = tid & 63;
    const int row = blockIdx.x * 4 + (tid >> 6);
    const int b = row >> 10;
    const int* mrow = mask + b * SS;
    const ushort* srow = su + (size_t)row * 2048;

    float e[4][4];
    float psum = 0.f;
#pragma unroll
    for (int g = 0; g < 4; g++) {
        const int t = g * 256 + lane * 4;
        const int4 mk = *(const int4*)(mrow + t);
        const ushort4 sv4 = *(const ushort4*)(srow + t);
        e[g][0] = __expf(bf2f(sv4.x) + (mk.x ? -1e9f : 0.0f));
        e[g][1] = __expf(bf2f(sv4.y) + (mk.y ? -1e9f : 0.0f));
        e[g][2] = __expf(bf2f(sv4.z) + (mk.z ? -1e9f : 0.0f));
        e[g][3] = __expf(bf2f(sv4.w) + (mk.w ? -1e9f : 0.0f));
        psum += e[g][0] + e[g][1] + e[g][2] + e[g][3];
    }
#pragma unroll
    for (int off = 32; off; off >>= 1) psum += __shfl_xor(psum, off);
    const float inv = 1.0f / psum;
    float* arow = a + (size_t)row * SS;
#pragma unroll
    for (int g = 0; g < 4; g++) {
        const int t = g * 256 + lane * 4;
        float4 o;
        o.x = e[g][0] * inv; o.y = e[g][1] * inv; o.z = e[g][2] * inv; o.w = e[g][3] * inv;
        *(float4*)(arow + t) = o;
    }
}

// ---------------------------------------------------------------- K4a: partial xbar[b][k] = sum_t a[b,0,t]*emb[tok[b,t]][k]
__global__ __launch_bounds__(256) void k_xbar(const float* __restrict__ a, const int* __restrict__ tokens,
                                              const float* __restrict__ emb, float* __restrict__ part) {
    const int b = blockIdx.x >> 3, c = blockIdx.x & 7;
    __shared__ float a0s[128];
    __shared__ int toks[128];
    const int tid = threadIdx.x;
    if (tid < 128) {
        a0s[tid] = a[(size_t)b * SS * SS + c * 128 + tid];
        toks[tid] = tokens[b * SS + c * 128 + tid];
    }
    __syncthreads();
    float acc0 = 0.f, acc1 = 0.f, acc2 = 0.f;
#pragma unroll 4
    for (int t = 0; t < 128; t++) {
        const float at = a0s[t];
        const float* er = emb + (size_t)toks[t] * DD;
        acc0 = fmaf(at, er[tid], acc0);
        acc1 = fmaf(at, er[tid + 256], acc1);
        acc2 = fmaf(at, er[tid + 512], acc2);
    }
    float* p = part + ((size_t)c * NB + b) * DD;
    p[tid] = acc0; p[tid + 256] = acc1; p[tid + 512] = acc2;
}

// ---------------------------------------------------------------- K5: cls[b][c] = sum_k xbar[b][k] * wv[k][c]
__global__ __launch_bounds__(128) void k_cls(const float* __restrict__ part, const float* __restrict__ wv,
                                             float* __restrict__ cls) {
    const int b = blockIdx.y, tid = threadIdx.x;
    const int c = blockIdx.x * 128 + tid;
    __shared__ float xb[DD];
#pragma unroll
    for (int j = 0; j < 6; j++) {
        const int k = tid + j * 128;
        float s = 0.f;
#pragma unroll
        for (int p = 0; p < 8; p++) s += part[((size_t)p * NB + b) * DD + k];
        xb[k] = s;
    }
    __syncthreads();
    float acc = 0.f;
#pragma unroll 8
    for (int k = 0; k < DD; k++) acc = fmaf(xb[k], wv[(size_t)k * DD + c], acc);
    cls[(size_t)b * DD + c] = acc;
}

__device__ inline float block_sum256(float v, float* red, int tid) {
#pragma unroll
    for (int off = 32; off; off >>= 1) v += __shfl_xor(v, off);
    __syncthreads();
    if ((tid & 63) == 0) red[tid >> 6] = v;
    __syncthreads();
    return red[0] + red[1] + red[2] + red[3];
}

// ---------------------------------------------------------------- K6: LayerNorm per batch
__global__ __launch_bounds__(256) void k_ln(const float* __restrict__ cls, const float* __restrict__ ln_g,
                                            const float* __restrict__ ln_b, float* __restrict__ hs) {
    const int b = blockIdx.x, tid = threadIdx.x;
    __shared__ float red[4];
    float v[3];
#pragma unroll
    for (int j = 0; j < 3; j++) v[j] = cls[(size_t)b * DD + tid + j * 256];
    const float mu = block_sum256(v[0] + v[1] + v[2], red, tid) * (1.0f / DD);
    float dv = 0.f;
#pragma unroll
    for (int j = 0; j < 3; j++) { const float d = v[j] - mu; dv += d * d; }
    __syncthreads();
    const float var = block_sum256(dv, red, tid) * (1.0f / DD);
    const float sc = 1.0f / sqrtf(var + 1e-5f);
#pragma unroll
    for (int j = 0; j < 3; j++) {
        const int d = tid + j * 256;
        hs[(size_t)b * DD + d] = (v[j] - mu) * sc * ln_g[d] + ln_b[d];
    }
}

// ---------------------------------------------------------------- K7: g = gelu(hs@w1+b1); partial logits per 128-col chunk
__global__ __launch_bounds__(128) void k_mlp(const float* __restrict__ hs, const float* __restrict__ w1,
                                             const float* __restrict__ b1, const float* __restrict__ wh,
                                             float* __restrict__ part_l) {
    const int b = blockIdx.y, tid = threadIdx.x;
    const int j = blockIdx.x * 128 + tid;
    __shared__ float h[DD];
#pragma unroll
    for (int q = 0; q < 6; q++) h[tid + q * 128] = hs[(size_t)b * DD + tid + q * 128];
    __syncthreads();
    float p = b1[j];
#pragma unroll 8
    for (int d = 0; d < DD; d++) p = fmaf(h[d], w1[(size_t)d * DD + j], p);
    const float g = 0.5f * p * (1.0f + erff(p * 0.70710678118654752f));
    float l0 = g * wh[j * 2 + 0];
    float l1 = g * wh[j * 2 + 1];
#pragma unroll
    for (int off = 32; off; off >>= 1) { l0 += __shfl_xor(l0, off); l1 += __shfl_xor(l1, off); }
    __shared__ float r0[2], r1[2];
    if ((tid & 63) == 0) { r0[tid >> 6] = l0; r1[tid >> 6] = l1; }
    __syncthreads();
    if (tid == 0) {
        part_l[((size_t)b * 6 + blockIdx.x) * 2 + 0] = r0[0] + r0[1];
        part_l[((size_t)b * 6 + blockIdx.x) * 2 + 1] = r1[0] + r1[1];
    }
}

// ---------------------------------------------------------------- K8: final logits reduce
__global__ __launch_bounds__(64) void k_final(const float* __restrict__ part_l, const float* __restrict__ bh,
                                              float* __restrict__ out) {
    const int b = threadIdx.x;
    if (b < NB) {
        float l0 = bh[0], l1 = bh[1];
#pragma unroll
        for (int c = 0; c < 6; c++) {
            l0 += part_l[((size_t)b * 6 + c) * 2 + 0];
            l1 += part_l[((size_t)b * 6 + c) * 2 + 1];
        }
        out[b * 2 + 0] = l0;
        out[b * 2 + 1] = l1;
    }
}

// ----------------------------------------------------------------
extern "C" void kernel_launch(void* const* d_in, const int* in_sizes, int n_in,
                              void* d_out, int out_size, void* d_ws, size_t ws_size,
                              hipStream_t stream) {
    const int*   tokens = (const int*)d_in[0];
    const int*   mask   = (const int*)d_in[1];
    const float* emb    = (const float*)d_in[2];
    const float* wq     = (const float*)d_in[3];
    const float* wk     = (const float*)d_in[4];
    const float* wv     = (const float*)d_in[5];
    const float* ln_g   = (const float*)d_in[6];
    const float* ln_b   = (const float*)d_in[7];
    const float* w1     = (const float*)d_in[8];
    const float* b1     = (const float*)d_in[9];
    const float* wh     = (const float*)d_in[10];
    const float* bh     = (const float*)d_in[11];
    float* out = (float*)d_out;

    char* ws = (char*)d_ws;
    const size_t XB = (size_t)NB * SS * DD * 2;   // 50,331,648 B
    const size_t WB = (size_t)DD * DD * 2;        // 1,179,648 B
    ushort* xb  = (ushort*)ws;                    // x bf16
    ushort* yb  = (ushort*)(ws + XB);             // y = x @ W bf16
    ushort* wqb = (ushort*)(ws + 2 * XB);         // wq bf16
    ushort* wkb = (ushort*)(ws + 2 * XB + WB);    // wk bf16
    ushort* Wt  = (ushort*)(ws + 2 * XB + 2 * WB);// Wt[e][d] = (wq wk^T)[d][e] bf16
    char*   p4  = ws + 2 * XB + 3 * WB;
    float*  part   = (float*)p4;                          // 8*32*768*4
    float*  cls    = (float*)(p4 + 786432);               // 32*768*4
    float*  hsb    = (float*)(p4 + 786432 + 98304);       // 32*768*4
    float*  part_l = (float*)(p4 + 786432 + 2 * 98304);   // 32*6*2*4

    float* a_region = out + 64;  // a: B*S*S floats

    k_cvt<<<dim3(576, 2), 256, 0, stream>>>(wq, wk, wqb, wkb);
    k_gather<<<24576, 256, 0, stream>>>(tokens, emb, xb);
    // Wt = wk @ wq^T  (Wt[e][d] = sum_j wk[e,j] wq[d,j] = W[d,e])
    k_gemm_s<<<dim3(6, 6), 256, 0, stream>>>(wkb, wqb, Wt);
    // y = x @ W  (balanced 1536-block grid, 2 blocks/CU)
    k_gemm_s<<<dim3(256, 6), 256, 0, stream>>>(xb, Wt, yb);
    // s = y @ x^T -> bf16, interleaved into a_region rows (first 2KB of each 4KB slot)
    k_gemm256b<<<512, 512, 0, stream>>>(yb, xb, (ushort*)a_region);
    // softmax: read own-row bf16, overwrite full row with f32 a
    k_smax<<<8192, 256, 0, stream>>>((const ushort*)a_region, mask, a_region);
    k_xbar<<<256, 256, 0, stream>>>(a_region, tokens, emb, part);
    k_cls<<<dim3(6, NB), 128, 0, stream>>>(part, wv, cls);
    k_ln<<<NB, 256, 0, stream>>>(cls, ln_g, ln_b, hsb);
    k_mlp<<<dim3(6, NB), 128, 0, stream>>>(hsb, w1, b1, wh, part_l);
    k_final<<<1, 64, 0, stream>>>(part_l, bh, out);
}

// Round 13
// 326.403 us; speedup vs baseline: 1.9000x; 1.0058x over previous
//
#include <hip/hip_runtime.h>
#include <hip/hip_bf16.h>

#define NB 32
#define SS 1024
#define DD 768

typedef __attribute__((ext_vector_type(8))) short bf16x8;
typedef __attribute__((ext_vector_type(4))) float f32x4;

__device__ inline ushort f2bf(float f) {
    union { float f; unsigned u; } x;
    x.f = f;
    unsigned r = (x.u + 0x7fffu + ((x.u >> 16) & 1u)) >> 16;
    return (ushort)r;
}

__device__ inline float bf2f(ushort u) {
    union { unsigned u; float f; } x;
    x.u = ((unsigned)u) << 16;
    return x.f;
}

#define GLOBAL_PTR(x) ((const __attribute__((address_space(1))) void*)(x))
#define LDS_PTR(x)    ((__attribute__((address_space(3))) void*)(x))

// ---------------------------------------------------------------- K0: gather x = bf16(emb[tokens]) + convert wq/wk -> bf16
// blocks [0, 24576): gather; blocks [24576, 25728): weight convert.
__global__ void k_prep(const int* __restrict__ tokens, const float* __restrict__ emb,
                       const float* __restrict__ wq, const float* __restrict__ wk,
                       ushort* __restrict__ xb, ushort* __restrict__ wqb, ushort* __restrict__ wkb) {
    const int bid = blockIdx.x;
    if (bid < 24576) {
        int i = (bid * 256 + threadIdx.x) * 4;
        int row = i / DD;
        int col = i - row * DD;
        int tok = tokens[row];
        const float4 v = *(const float4*)(emb + (size_t)tok * DD + col);
        ushort4 o;
        o.x = f2bf(v.x); o.y = f2bf(v.y); o.z = f2bf(v.z); o.w = f2bf(v.w);
        *(ushort4*)(xb + (size_t)row * DD + col) = o;
    } else {
        const int b2 = bid - 24576;
        const float* src = (b2 < 576) ? wq : wk;
        ushort* dst = (b2 < 576) ? wqb : wkb;
        const int local = (b2 < 576) ? b2 : b2 - 576;
        const int i = (local * 256 + threadIdx.x) * 4;
        const float4 v = *(const float4*)(src + i);
        ushort4 o;
        o.x = f2bf(v.x); o.y = f2bf(v.y); o.z = f2bf(v.z); o.w = f2bf(v.w);
        *(ushort4*)(dst + i) = o;
    }
}

// ---------------------------------------------------------------- 128x128 GEMM (m97 structure, dbuf): C = A@Bt^T, bf16 out
__global__ __launch_bounds__(256, 2) void k_gemm_s(const ushort* __restrict__ A,
                                                   const ushort* __restrict__ Bt,
                                                   ushort* __restrict__ Cb) {
    constexpr int BK = 64;
    __shared__ ushort As[2][128 * BK];
    __shared__ ushort Bs[2][128 * BK];
    const int tid = threadIdx.x;
    const int wave = tid >> 6, lane = tid & 63;
    const int bx = blockIdx.x, by = blockIdx.y;
    const size_t abase = (size_t)bx * 128 * DD;
    const size_t bbase = (size_t)by * 128 * DD;
    const int r = tid >> 3;
    const int cc = (tid & 7) * 8;

    auto stage = [&](int buf, int k0) {
#pragma unroll
        for (int i = 0; i < 4; i++) {
            __builtin_amdgcn_global_load_lds(GLOBAL_PTR(A + abase + (size_t)(r + i * 32) * DD + k0 + cc),
                                             LDS_PTR(&As[buf][(r + i * 32) * BK + cc]), 16, 0, 0);
            __builtin_amdgcn_global_load_lds(GLOBAL_PTR(Bt + bbase + (size_t)(r + i * 32) * DD + k0 + cc),
                                             LDS_PTR(&Bs[buf][(r + i * 32) * BK + cc]), 16, 0, 0);
        }
    };

    f32x4 acc[4][4] = {};
    const int wm = (wave >> 1) * 64, wn = (wave & 1) * 64;
    const int lr = lane & 15, lc = (lane >> 4) * 8;

    stage(0, 0);
    __syncthreads();
    int cur = 0;
#pragma unroll 1
    for (int k0 = 0; k0 < DD; k0 += BK) {
        if (k0 + BK < DD) stage(cur ^ 1, k0 + BK);
        const ushort* as = As[cur];
        const ushort* bs = Bs[cur];
#pragma unroll
        for (int kk = 0; kk < 2; kk++) {
            bf16x8 af[4], bfv[4];
#pragma unroll
            for (int m = 0; m < 4; m++)
                af[m] = *(const bf16x8*)(as + (wm + m * 16 + lr) * BK + kk * 32 + lc);
#pragma unroll
            for (int n = 0; n < 4; n++)
                bfv[n] = *(const bf16x8*)(bs + (wn + n * 16 + lr) * BK + kk * 32 + lc);
#pragma unroll
            for (int m = 0; m < 4; m++)
#pragma unroll
                for (int n = 0; n < 4; n++)
                    acc[m][n] = __builtin_amdgcn_mfma_f32_16x16x32_bf16(af[m], bfv[n], acc[m][n], 0, 0, 0);
        }
        __syncthreads();
        cur ^= 1;
    }
    const int rowbase = bx * 128 + wm + (lane >> 4) * 4;
    const int colbase = by * 128 + wn + (lane & 15);
#pragma unroll
    for (int m = 0; m < 4; m++)
#pragma unroll
        for (int n = 0; n < 4; n++)
#pragma unroll
            for (int j = 0; j < 4; j++)
                Cb[(size_t)(rowbase + m * 16 + j) * DD + colbase + n * 16] = f2bf(acc[m][n][j]);
}

// ---------------------------------------------------------------- 256x256 8-wave 4-phase GEMM for batched QK^T.
// Change vs R12: ALL 4 half-tile prefetches issue at q==0 (issue-early), so the
// boundary __syncthreads' vmcnt(0) drain finds them already landed. Barriers and
// buffer discipline unchanged (R5-proven). Output: bf16 s interleaved into the
// f32 a-region (first 2KB of each row's 4KB slot; row stride 2048 ushorts).
#define HALF_USH (128 * 64)
__global__ __launch_bounds__(512, 2) void k_gemm256b(const ushort* __restrict__ A,
                                                     const ushort* __restrict__ Bt,
                                                     ushort* __restrict__ Cu) {
    __shared__ ushort As[2][2][HALF_USH];
    __shared__ ushort Bs[2][2][HALF_USH];
    const int tid = threadIdx.x;
    const int wid = tid >> 6, lane = tid & 63;
    const int wm = wid >> 2, wn = wid & 3;
    const int la = lane & 15;

    const int wgid = blockIdx.x;
    const int g = wgid >> 7, w = wgid & 127;
    const int b = g * 8 + (w & 7);
    const int tile = w >> 3;
    const int bx = tile & 3, by = tile >> 2;
    const ushort* Ag = A + (size_t)b * SS * DD + (size_t)bx * 256 * DD;
    const ushort* Bg = Bt + (size_t)b * SS * DD + (size_t)by * 256 * DD;
    Cu += (size_t)b * SS * 2048;

    int s_r[2], s_c[2], s_d[2];
#pragma unroll
    for (int l = 0; l < 2; l++) {
        const int L = (l * 512 + tid) * 16;
        const int r = L >> 7;
        const int cb = L & 127;
        s_r[l] = r;
        s_c[l] = (cb ^ ((r & 7) << 4)) >> 1;
        s_d[l] = L >> 1;
    }

    auto stage_half = [&](ushort* dst, const ushort* gsrc) {
#pragma unroll
        for (int l = 0; l < 2; l++)
            __builtin_amdgcn_global_load_lds(GLOBAL_PTR(gsrc + (size_t)s_r[l] * DD + s_c[l]),
                                             LDS_PTR(dst + s_d[l]), 16, 0, 0);
    };

    const int swz = (la & 7) << 4;
    const int off_k0 = (((lane >> 4) << 4) ^ swz) >> 1;
    const int off_k1 = ((64 | ((lane >> 4) << 4)) ^ swz) >> 1;

    f32x4 acc[8][4] = {};

    stage_half(&As[0][0][0], Ag);
    stage_half(&As[0][1][0], Ag + (size_t)128 * DD);
    stage_half(&Bs[0][0][0], Bg);
    stage_half(&Bs[0][1][0], Bg + (size_t)128 * DD);
    __syncthreads();

#pragma unroll 1
    for (int t = 0; t < 12; t++) {
        const int buf = t & 1;
        const ushort* Ah = &As[buf][wm][0];
        const ushort* Bh = &Bs[buf][wn >> 1][0];
        const int brow0 = (wn & 1) * 64;
        const int kt = (t + 1) * 64;
        bf16x8 bfv[4][2];
#pragma unroll
        for (int q = 0; q < 4; q++) {
            if (q == 0) {
#pragma unroll
                for (int n = 0; n < 4; n++) {
                    const int rr = brow0 + n * 16 + la;
                    bfv[n][0] = *(const bf16x8*)(Bh + rr * 64 + off_k0);
                    bfv[n][1] = *(const bf16x8*)(Bh + rr * 64 + off_k1);
                }
                if (t < 11) {   // issue-early: all 4 halves of tile t+1 now
                    stage_half(&As[buf ^ 1][0][0], Ag + kt);
                    stage_half(&As[buf ^ 1][1][0], Ag + (size_t)128 * DD + kt);
                    stage_half(&Bs[buf ^ 1][0][0], Bg + kt);
                    stage_half(&Bs[buf ^ 1][1][0], Bg + (size_t)128 * DD + kt);
                }
            }
            bf16x8 af[2][2];
#pragma unroll
            for (int dm = 0; dm < 2; dm++) {
                const int rr = (q * 2 + dm) * 16 + la;
                af[dm][0] = *(const bf16x8*)(Ah + rr * 64 + off_k0);
                af[dm][1] = *(const bf16x8*)(Ah + rr * 64 + off_k1);
            }
            __builtin_amdgcn_s_setprio(1);
#pragma unroll
            for (int dm = 0; dm < 2; dm++)
#pragma unroll
                for (int n = 0; n < 4; n++)
#pragma unroll
                    for (int kk = 0; kk < 2; kk++)
                        acc[q * 2 + dm][n] = __builtin_amdgcn_mfma_f32_16x16x32_bf16(
                            af[dm][kk], bfv[n][kk], acc[q * 2 + dm][n], 0, 0, 0);
            __builtin_amdgcn_s_setprio(0);
            if (q < 3) __builtin_amdgcn_s_barrier();
        }
        __syncthreads();
    }

    const int rowbase = bx * 256 + wm * 128 + (lane >> 4) * 4;
    const int colbase = by * 256 + wn * 64 + la;
#pragma unroll
    for (int m = 0; m < 8; m++)
#pragma unroll
        for (int n = 0; n < 4; n++)
#pragma unroll
            for (int j = 0; j < 4; j++)
                Cu[(size_t)(rowbase + m * 16 + j) * 2048 + colbase + n * 16] = f2bf(acc[m][n][j]);
}

// ---------------------------------------------------------------- masked softmax: one wave per row; reads bf16 s from the
// first 2KB of the row's own 4KB slot, overwrites the full slot with f32 a.
__global__ __launch_bounds__(256) void k_smax(const ushort* __restrict__ su, const int* __restrict__ mask,
                                              float* __restrict__ a) {
    const int tid = threadIdx.x, lane = tid & 63;
    const int row = blockIdx.x * 4 + (tid >> 6);
    const int b = row >> 10;
    const int* mrow = mask + b * SS;
    const ushort* srow = su + (size_t)row * 2048;

    float e[4][4];
    float psum = 0.f;
#pragma unroll
    for (int g = 0; g < 4; g++) {
        const int t = g * 256 + lane * 4;
        const int4 mk = *(const int4*)(mrow + t);
        const ushort4 sv4 = *(const ushort4*)(srow + t);
        e[g][0] = __expf(bf2f(sv4.x) + (mk.x ? -1e9f : 0.0f));
        e[g][1] = __expf(bf2f(sv4.y) + (mk.y ? -1e9f : 0.0f));
        e[g][2] = __expf(bf2f(sv4.z) + (mk.z ? -1e9f : 0.0f));
        e[g][3] = __expf(bf2f(sv4.w) + (mk.w ? -1e9f : 0.0f));
        psum += e[g][0] + e[g][1] + e[g][2] + e[g][3];
    }
#pragma unroll
    for (int off = 32; off; off >>= 1) psum += __shfl_xor(psum, off);
    const float inv = 1.0f / psum;
    float* arow = a + (size_t)row * SS;
#pragma unroll
    for (int g = 0; g < 4; g++) {
        const int t = g * 256 + lane * 4;
        float4 o;
        o.x = e[g][0] * inv; o.y = e[g][1] * inv; o.z = e[g][2] * inv; o.w = e[g][3] * inv;
        *(float4*)(arow + t) = o;
    }
}

// ---------------------------------------------------------------- K4a: partial xbar[b][k] = sum_t a[b,0,t]*emb[tok[b,t]][k]
__global__ __launch_bounds__(256) void k_xbar(const float* __restrict__ a, const int* __restrict__ tokens,
                                              const float* __restrict__ emb, float* __restrict__ part) {
    const int b = blockIdx.x >> 3, c = blockIdx.x & 7;
    __shared__ float a0s[128];
    __shared__ int toks[128];
    const int tid = threadIdx.x;
    if (tid < 128) {
        a0s[tid] = a[(size_t)b * SS * SS + c * 128 + tid];
        toks[tid] = tokens[b * SS + c * 128 + tid];
    }
    __syncthreads();
    float acc0 = 0.f, acc1 = 0.f, acc2 = 0.f;
#pragma unroll 4
    for (int t = 0; t < 128; t++) {
        const float at = a0s[t];
        const float* er = emb + (size_t)toks[t] * DD;
        acc0 = fmaf(at, er[tid], acc0);
        acc1 = fmaf(at, er[tid + 256], acc1);
        acc2 = fmaf(at, er[tid + 512], acc2);
    }
    float* p = part + ((size_t)c * NB + b) * DD;
    p[tid] = acc0; p[tid + 256] = acc1; p[tid + 512] = acc2;
}

// ---------------------------------------------------------------- K5: cls[b][c] = sum_k xbar[b][k] * wv[k][c]
__global__ __launch_bounds__(128) void k_cls(const float* __restrict__ part, const float* __restrict__ wv,
                                             float* __restrict__ cls) {
    const int b = blockIdx.y, tid = threadIdx.x;
    const int c = blockIdx.x * 128 + tid;
    __shared__ float xb[DD];
#pragma unroll
    for (int j = 0; j < 6; j++) {
        const int k = tid + j * 128;
        float s = 0.f;
#pragma unroll
        for (int p = 0; p < 8; p++) s += part[((size_t)p * NB + b) * DD + k];
        xb[k] = s;
    }
    __syncthreads();
    float acc = 0.f;
#pragma unroll 8
    for (int k = 0; k < DD; k++) acc = fmaf(xb[k], wv[(size_t)k * DD + c], acc);
    cls[(size_t)b * DD + c] = acc;
}

// ---------------------------------------------------------------- K7: LN (in-block, redundant per col-chunk) + gelu MLP +
// partial logits. grid (6, 32), 128 thr.
__global__ __launch_bounds__(128) void k_mlp(const float* __restrict__ cls, const float* __restrict__ ln_g,
                                             const float* __restrict__ ln_b, const float* __restrict__ w1,
                                             const float* __restrict__ b1, const float* __restrict__ wh,
                                             float* __restrict__ part_l) {
    const int b = blockIdx.y, tid = threadIdx.x;
    __shared__ float h[DD];
    __shared__ float red2[2];
    float v[6];
#pragma unroll
    for (int q = 0; q < 6; q++) v[q] = cls[(size_t)b * DD + tid + q * 128];
    float s = v[0] + v[1] + v[2] + v[3] + v[4] + v[5];
#pragma unroll
    for (int off = 32; off; off >>= 1) s += __shfl_xor(s, off);
    if ((tid & 63) == 0) red2[tid >> 6] = s;
    __syncthreads();
    const float mu = (red2[0] + red2[1]) * (1.0f / DD);
    float dv = 0.f;
#pragma unroll
    for (int q = 0; q < 6; q++) { const float d = v[q] - mu; dv += d * d; }
#pragma unroll
    for (int off = 32; off; off >>= 1) dv += __shfl_xor(dv, off);
    __syncthreads();
    if ((tid & 63) == 0) red2[tid >> 6] = dv;
    __syncthreads();
    const float var = (red2[0] + red2[1]) * (1.0f / DD);
    const float sc = 1.0f / sqrtf(var + 1e-5f);
#pragma unroll
    for (int q = 0; q < 6; q++) {
        const int d = tid + q * 128;
        h[d] = (v[q] - mu) * sc * ln_g[d] + ln_b[d];
    }
    __syncthreads();

    const int j = blockIdx.x * 128 + tid;
    float p = b1[j];
#pragma unroll 8
    for (int d = 0; d < DD; d++) p = fmaf(h[d], w1[(size_t)d * DD + j], p);
    const float g = 0.5f * p * (1.0f + erff(p * 0.70710678118654752f));
    float l0 = g * wh[j * 2 + 0];
    float l1 = g * wh[j * 2 + 1];
#pragma unroll
    for (int off = 32; off; off >>= 1) { l0 += __shfl_xor(l0, off); l1 += __shfl_xor(l1, off); }
    __shared__ float r0[2], r1[2];
    if ((tid & 63) == 0) { r0[tid >> 6] = l0; r1[tid >> 6] = l1; }
    __syncthreads();
    if (tid == 0) {
        part_l[((size_t)b * 6 + blockIdx.x) * 2 + 0] = r0[0] + r0[1];
        part_l[((size_t)b * 6 + blockIdx.x) * 2 + 1] = r1[0] + r1[1];
    }
}

// ---------------------------------------------------------------- K8: final logits reduce
__global__ __launch_bounds__(64) void k_final(const float* __restrict__ part_l, const float* __restrict__ bh,
                                              float* __restrict__ out) {
    const int b = threadIdx.x;
    if (b < NB) {
        float l0 = bh[0], l1 = bh[1];
#pragma unroll
        for (int c = 0; c < 6; c++) {
            l0 += part_l[((size_t)b * 6 + c) * 2 + 0];
            l1 += part_l[((size_t)b * 6 + c) * 2 + 1];
        }
        out[b * 2 + 0] = l0;
        out[b * 2 + 1] = l1;
    }
}

// ----------------------------------------------------------------
extern "C" void kernel_launch(void* const* d_in, const int* in_sizes, int n_in,
                              void* d_out, int out_size, void* d_ws, size_t ws_size,
                              hipStream_t stream) {
    const int*   tokens = (const int*)d_in[0];
    const int*   mask   = (const int*)d_in[1];
    const float* emb    = (const float*)d_in[2];
    const float* wq     = (const float*)d_in[3];
    const float* wk     = (const float*)d_in[4];
    const float* wv     = (const float*)d_in[5];
    const float* ln_g   = (const float*)d_in[6];
    const float* ln_b   = (const float*)d_in[7];
    const float* w1     = (const float*)d_in[8];
    const float* b1     = (const float*)d_in[9];
    const float* wh     = (const float*)d_in[10];
    const float* bh     = (const float*)d_in[11];
    float* out = (float*)d_out;

    char* ws = (char*)d_ws;
    const size_t XB = (size_t)NB * SS * DD * 2;   // 50,331,648 B
    const size_t WB = (size_t)DD * DD * 2;        // 1,179,648 B
    ushort* xb  = (ushort*)ws;                    // x bf16
    ushort* yb  = (ushort*)(ws + XB);             // y = x @ W bf16
    ushort* wqb = (ushort*)(ws + 2 * XB);         // wq bf16
    ushort* wkb = (ushort*)(ws + 2 * XB + WB);    // wk bf16
    ushort* Wt  = (ushort*)(ws + 2 * XB + 2 * WB);// Wt[e][d] = (wq wk^T)[d][e] bf16
    char*   p4  = ws + 2 * XB + 3 * WB;
    float*  part   = (float*)p4;                          // 8*32*768*4
    float*  cls    = (float*)(p4 + 786432);               // 32*768*4
    float*  part_l = (float*)(p4 + 786432 + 98304);       // 32*6*2*4

    float* a_region = out + 64;  // a: B*S*S floats

    // gather + weight convert (merged)
    k_prep<<<24576 + 1152, 256, 0, stream>>>(tokens, emb, wq, wk, xb, wqb, wkb);
    // Wt = wk @ wq^T  (Wt[e][d] = sum_j wk[e,j] wq[d,j] = W[d,e])
    k_gemm_s<<<dim3(6, 6), 256, 0, stream>>>(wkb, wqb, Wt);
    // y = x @ W  (balanced 1536-block grid, 2 blocks/CU)
    k_gemm_s<<<dim3(256, 6), 256, 0, stream>>>(xb, Wt, yb);
    // s = y @ x^T -> bf16 interleaved into a_region (issue-early staging)
    k_gemm256b<<<512, 512, 0, stream>>>(yb, xb, (ushort*)a_region);
    // softmax: read own-row bf16, overwrite full row with f32 a
    k_smax<<<8192, 256, 0, stream>>>((const ushort*)a_region, mask, a_region);
    k_xbar<<<256, 256, 0, stream>>>(a_region, tokens, emb, part);
    k_cls<<<dim3(6, NB), 128, 0, stream>>>(part, wv, cls);
    k_mlp<<<dim3(6, NB), 128, 0, stream>>>(cls, ln_g, ln_b, w1, b1, wh, part_l);
    k_final<<<1, 64, 0, stream>>>(part_l, bh, out);
}